// Round 11
// baseline (201.826 us; speedup 1.0000x reference)
//
#include <hip/hip_runtime.h>

#define DIM   128
#define DMASK 127
#define PLANE (DIM * DIM)     // 16384
#define VOX   (1 << 21)       // 128^3
#define NCH   12

typedef __attribute__((ext_vector_type(2))) _Float16 half2v;
typedef __attribute__((ext_vector_type(4))) _Float16 half4v;
typedef __attribute__((ext_vector_type(8))) _Float16 half8v;

#define D2S 140               // D2p row stride (halves): 70 words % 32 = 6
#define T1S 132               // T1 row stride (floats): 132 % 32 = 4

// Per-channel shift pairs (d,h,w) = 2*(one_hot_idx - 1); verified (absmax 0).
__constant__ int c_sd1[12] = { 0, 0, 0, 0, 0, 2, 2, 2, 0, 0, 0, 0};
__constant__ int c_sh1[12] = { 0,-2,-2, 0, 0, 0, 0, 0, 2, 2, 2, 2};
__constant__ int c_sw1[12] = {-2, 0, 0, 2, 2, 0, 0, 0, 0, 0, 0, 0};
__constant__ int c_sd2[12] = {-2,-2, 0,-2, 0, 0, 0, 0,-2, 0, 0, 2};
__constant__ int c_sh2[12] = { 0, 0, 0, 0,-2, 0,-2, 0, 0, 0, 0, 0};
__constant__ int c_sw2[12] = { 0, 0,-2, 0, 0,-2, 0, 2, 0,-2, 2, 0};

__device__ __forceinline__ int clamp7(int v) { return min(max(v, 0), DMASK); }

// F123: diff^2 + W-box + H-box + D-box, writing ssd directly.
// Padded LDS strides kill the 8-way T1-write / 4-way D2p-read conflicts.
__global__ __launch_bounds__(256) void f123(const float* __restrict__ img0,
                                            const float* __restrict__ img1,
                                            _Float16* __restrict__ Sall) {
    const float* img = blockIdx.y ? img1 : img0;
    _Float16* outS = Sall + (size_t)blockIdx.y * NCH * VOX;

    int b  = blockIdx.x;            // 384 = 12 ch * 4 hq * 8 dseg
    int ch = b >> 5;
    int hq = (b >> 3) & 3;
    int ds = b & 7;
    int h0 = hq << 5;
    int d0 = ds << 4;
    int tid = threadIdx.x;

    __shared__ int rowA[36], rowB[36];
    __shared__ __align__(16) _Float16 D2p[36 * D2S];
    __shared__ __align__(16) float    T1[36 * T1S];

    int sd1 = c_sd1[ch], sh1 = c_sh1[ch], sw1 = c_sw1[ch];
    int sd2 = c_sd2[ch], sh2 = c_sh2[ch], sw2 = c_sw2[ch];

    if (tid < 36) {
        int hqr = clamp7(h0 - 2 + tid);
        rowA[tid] = clamp7(hqr + sh1) * (DIM * 4);
        rowB[tid] = clamp7(hqr + sh2) * (DIM * 4);
    }
    __syncthreads();

    int l  = tid & 63;              // phase1 interior lane
    int rr = tid >> 6;
    int wp  = (tid & 63) << 1;      // phase3: column pair
    int lh0 = (tid >> 6) << 3;      // phase3: first of 8 rows

    int cAi = 0, cBi = 0;
    if (l < 62) {
        int j0 = 4 + (l << 1);
        cAi = (j0 - 2 + sw1) * 4;
        cBi = (j0 - 2 + sw2) * 4;
    }

    float2 win[8];
    half2v hist[5][8];
#pragma unroll
    for (int k = 0; k < 8; ++k) {
        win[k].x = 0.0f; win[k].y = 0.0f;
#pragma unroll
        for (int s = 0; s < 5; ++s) hist[s][k] = half2v{(_Float16)0.0f, (_Float16)0.0f};
    }

    _Float16* dstBase = outS + (size_t)ch * VOX + (h0 + lh0) * DIM + wp;

    for (int oo = 0; oo < 4; ++oo) {
#pragma unroll
        for (int s = 0; s < 5; ++s) {
            int it = oo * 5 + s;
            int dp = clamp7(d0 - 2 + it);
            const char* pA = (const char*)(img + clamp7(dp + sd1) * PLANE);
            const char* pB = (const char*)(img + clamp7(dp + sd2) * PLANE);

            // phase 1 interior: unclamped float2 loads, j0 in [4,126]
            if (l < 62) {
                int j0 = 4 + (l << 1);
#pragma unroll
                for (int k = 0; k < 9; ++k) {
                    int r = rr + (k << 2);
                    float2 a = *(const float2*)(pA + rowA[r] + cAi);
                    float2 c = *(const float2*)(pB + rowB[r] + cBi);
                    float e0 = a.x - c.x, e1 = a.y - c.y;
                    half2v hv = { (_Float16)(e0 * e0), (_Float16)(e1 * e1) };
                    *(half2v*)&D2p[r * D2S + j0] = hv;
                }
            }
            // phase 1 edges: j0 in {0,2,128,130}, scalar double-clamp
            if (tid < 144) {
                int r  = tid >> 2;
                int pe = tid & 3;
                int j0 = (pe < 2) ? (pe << 1) : (124 + (pe << 1));
                int ra = rowA[r], rb = rowB[r];
                float dd[2];
#pragma unroll
                for (int e = 0; e < 2; ++e) {
                    int wq = clamp7(j0 + e - 2);
                    float a = *(const float*)(pA + ra + clamp7(wq + sw1) * 4);
                    float c = *(const float*)(pB + rb + clamp7(wq + sw2) * 4);
                    float df = a - c;
                    dd[e] = df * df;
                }
                half2v hv = { (_Float16)dd[0], (_Float16)dd[1] };
                *(half2v*)&D2p[r * D2S + j0] = hv;
            }
            __syncthreads();

            // phase 2: W-box, 4 outputs/unit
            for (int i = tid; i < 36 * 32; i += 256) {
                int r = i >> 5;
                int g = (i & 31) << 2;
                const half4v* src = (const half4v*)&D2p[r * D2S + g];
                half4v lo = src[0], hi = src[1];
                float l0 = lo[0], l1 = lo[1], l2 = lo[2], l3 = lo[3];
                float u0 = hi[0], u1 = hi[1], u2 = hi[2], u3 = hi[3];
                float o0 = l0 + l1 + l2 + l3 + u0;
                float o1 = o0 - l0 + u1;
                float o2 = o1 - l1 + u2;
                float o3 = o2 - l2 + u3;
                *(float4*)&T1[r * T1S + g] = make_float4(o0, o1, o2, o3);
            }
            __syncthreads();

            // phase 3: H-box (sliding 5-row col sums) -> D-window update
            {
                const float* base = &T1[lh0 * T1S + wp];
                float rx[12], ry[12];
#pragma unroll
                for (int k = 0; k < 12; ++k) {
                    float2 v = *(const float2*)(base + k * T1S);
                    rx[k] = v.x; ry[k] = v.y;
                }
                float sx = rx[0] + rx[1] + rx[2] + rx[3] + rx[4];
                float sy = ry[0] + ry[1] + ry[2] + ry[3] + ry[4];
                bool dowrite = (it >= 4);
                _Float16* dstD = dstBase + (size_t)(d0 + it - 4) * PLANE;
#pragma unroll
                for (int k = 0; k < 8; ++k) {
                    half2v hv = { (_Float16)sx, (_Float16)sy };  // round first
                    half2v old = hist[s][k];
                    win[k].x += (float)hv[0] - (float)old[0];
                    win[k].y += (float)hv[1] - (float)old[1];
                    hist[s][k] = hv;
                    if (dowrite) {
                        half2v ov = { (_Float16)win[k].x, (_Float16)win[k].y };
                        *(half2v*)(dstD + k * DIM) = ov;
                    }
                    if (k < 7) {
                        sx += rx[k + 5] - rx[k];
                        sy += ry[k + 5] - ry[k];
                    }
                }
            }
            // safe without sync: phase1 (D2p) is fenced by the sync after it;
            // phase3's T1 readers finish before the next phase2 write (which
            // is after that sync).
        }
    }
}

// kmse v5: 8 vox/thread, 16-B half8v loads, e0 overwrites v regs (fp16 e0
// validated r5-r9), ZERO atomics: one partial per block -> kred sums.
__global__ __launch_bounds__(256, 3) void kmse(const _Float16* __restrict__ S0,
                                               const _Float16* __restrict__ S1,
                                               float* __restrict__ partial) {
    int t = blockIdx.x * 256 + threadIdx.x;       // 1024 blocks

    float mn[8], sm[8];
    half8v v[NCH];

    // ---- img0: 12 fat loads, min/sum, e0 in place ----
#pragma unroll
    for (int ch = 0; ch < NCH; ++ch)
        v[ch] = ((const half8v*)(S0 + ((size_t)ch << 21)))[t];
#pragma unroll
    for (int j = 0; j < 8; ++j) { mn[j] = 3.4e38f; sm[j] = 0.0f; }
#pragma unroll
    for (int ch = 0; ch < NCH; ++ch)
#pragma unroll
        for (int j = 0; j < 8; ++j) {
            float s = (float)v[ch][j];
            mn[j] = fminf(mn[j], s); sm[j] += s;
        }
    float inv[8];
#pragma unroll
    for (int j = 0; j < 8; ++j)
        inv[j] = __fdividef(1.0f, sm[j] * (1.0f / 12.0f) - mn[j]);
#pragma unroll
    for (int ch = 0; ch < NCH; ++ch) {
        half8v e;
#pragma unroll
        for (int j = 0; j < 8; ++j)
            e[j] = (_Float16)__expf(-((float)v[ch][j] - mn[j]) * inv[j]);
        v[ch] = e;                                 // e0 kept in the same regs
    }
    half8v e0[NCH];
#pragma unroll
    for (int ch = 0; ch < NCH; ++ch) e0[ch] = v[ch];

    // ---- img1: 12 fat loads, min/sum ----
#pragma unroll
    for (int ch = 0; ch < NCH; ++ch)
        v[ch] = ((const half8v*)(S1 + ((size_t)ch << 21)))[t];
#pragma unroll
    for (int j = 0; j < 8; ++j) { mn[j] = 3.4e38f; sm[j] = 0.0f; }
#pragma unroll
    for (int ch = 0; ch < NCH; ++ch)
#pragma unroll
        for (int j = 0; j < 8; ++j) {
            float s = (float)v[ch][j];
            mn[j] = fminf(mn[j], s); sm[j] += s;
        }
#pragma unroll
    for (int j = 0; j < 8; ++j)
        inv[j] = __fdividef(1.0f, sm[j] * (1.0f / 12.0f) - mn[j]);

    // ---- MSE ----
    float acc = 0.0f;
#pragma unroll
    for (int ch = 0; ch < NCH; ++ch)
#pragma unroll
        for (int j = 0; j < 8; ++j) {
            float e1 = __expf(-((float)v[ch][j] - mn[j]) * inv[j]);
            float df = (float)e0[ch][j] - e1;
            acc += df * df;
        }

    // block reduce -> one contention-free store per block
#pragma unroll
    for (int off = 32; off > 0; off >>= 1)
        acc += __shfl_down(acc, off, 64);
    __shared__ float smem[4];
    int lane = threadIdx.x & 63, wv = threadIdx.x >> 6;
    if (lane == 0) smem[wv] = acc;
    __syncthreads();
    if (threadIdx.x == 0)
        partial[blockIdx.x] = smem[0] + smem[1] + smem[2] + smem[3];
}

// kred: sum 1024 partials, write the final scalar.
__global__ __launch_bounds__(256) void kred(const float* __restrict__ partial,
                                            float* __restrict__ out) {
    int tid = threadIdx.x;
    float acc = partial[tid] + partial[tid + 256]
              + partial[tid + 512] + partial[tid + 768];
#pragma unroll
    for (int off = 32; off > 0; off >>= 1)
        acc += __shfl_down(acc, off, 64);
    __shared__ float smem[4];
    int lane = tid & 63, wv = tid >> 6;
    if (lane == 0) smem[wv] = acc;
    __syncthreads();
    if (tid == 0)
        out[0] = (smem[0] + smem[1] + smem[2] + smem[3])
               * (1.0f / (12.0f * (float)VOX));
}

__global__ void kdiag(float* out, float ws_mb) { out[0] = ws_mb; }

extern "C" void kernel_launch(void* const* d_in, const int* in_sizes, int n_in,
                              void* d_out, int out_size, void* d_ws, size_t ws_size,
                              hipStream_t stream) {
    const float* y_true = (const float*)d_in[0];
    const float* y_pred = (const float*)d_in[1];
    float* out = (float*)d_out;

    const size_t NEED = 2ull * NCH * VOX * sizeof(_Float16) + 4096 + 64;
    if (ws_size < NEED) {
        kdiag<<<1, 1, 0, stream>>>(out, (float)(ws_size >> 20));
        return;
    }

    _Float16* S0      = (_Float16*)d_ws;                 // 48 MB (ssd img0)
    _Float16* S1      = S0 + (size_t)NCH * VOX;          // 48 MB (ssd img1)
    float*    partial = (float*)(S1 + (size_t)NCH * VOX);// 1024 floats

    f123<<<dim3(12 * 4 * 8, 2), 256, 0, stream>>>(y_true, y_pred, S0);
    kmse<<<VOX / 8 / 256, 256, 0, stream>>>(S0, S1, partial);
    kred<<<1, 256, 0, stream>>>(partial, out);
}

// Round 12
// 142.236 us; speedup vs baseline: 1.4189x; 1.4189x over previous
//
#include <hip/hip_runtime.h>

#define DIM   128
#define DMASK 127
#define PLANE (DIM * DIM)     // 16384
#define VOX   (1 << 21)       // 128^3
#define NCH   12

// De-aliased layout: channel stride = 4 MB + 4 KB (in halves), image stride
// adds another 2 KB. Breaks the 24x 4MB-aligned stream bases that were
// serializing on the L3/HBM channel hash (theory: r10/r11 1.2 TB/s walls).
#define CHS   (VOX + 2048)
#define IMGS  (NCH * CHS + 1024)

typedef __attribute__((ext_vector_type(2))) _Float16 half2v;
typedef __attribute__((ext_vector_type(4))) _Float16 half4v;

#define D2S 136               // reverted r11 padding (it regressed f123)
#define T1S 128

// Per-channel shift pairs (d,h,w) = 2*(one_hot_idx - 1); verified (absmax 0).
__constant__ int c_sd1[12] = { 0, 0, 0, 0, 0, 2, 2, 2, 0, 0, 0, 0};
__constant__ int c_sh1[12] = { 0,-2,-2, 0, 0, 0, 0, 0, 2, 2, 2, 2};
__constant__ int c_sw1[12] = {-2, 0, 0, 2, 2, 0, 0, 0, 0, 0, 0, 0};
__constant__ int c_sd2[12] = {-2,-2, 0,-2, 0, 0, 0, 0,-2, 0, 0, 2};
__constant__ int c_sh2[12] = { 0, 0, 0, 0,-2, 0,-2, 0, 0, 0, 0, 0};
__constant__ int c_sw2[12] = { 0, 0,-2, 0, 0,-2, 0, 2, 0,-2, 2, 0};

__device__ __forceinline__ int clamp7(int v) { return min(max(v, 0), DMASK); }

// F123 (r10 structure): diff^2 + W-box + H-box + D-box, writes ssd directly.
__global__ __launch_bounds__(256) void f123(const float* __restrict__ img0,
                                            const float* __restrict__ img1,
                                            _Float16* __restrict__ Sall) {
    const float* img = blockIdx.y ? img1 : img0;
    _Float16* outS = Sall + (size_t)blockIdx.y * IMGS;

    int b  = blockIdx.x;            // 384 = 12 ch * 4 hq * 8 dseg
    int ch = b >> 5;
    int hq = (b >> 3) & 3;
    int ds = b & 7;
    int h0 = hq << 5;
    int d0 = ds << 4;
    int tid = threadIdx.x;

    __shared__ int rowA[36], rowB[36];
    __shared__ __align__(16) _Float16 D2p[36 * D2S];
    __shared__ __align__(16) float    T1[36 * T1S];

    int sd1 = c_sd1[ch], sh1 = c_sh1[ch], sw1 = c_sw1[ch];
    int sd2 = c_sd2[ch], sh2 = c_sh2[ch], sw2 = c_sw2[ch];

    if (tid < 36) {
        int hqr = clamp7(h0 - 2 + tid);
        rowA[tid] = clamp7(hqr + sh1) * (DIM * 4);
        rowB[tid] = clamp7(hqr + sh2) * (DIM * 4);
    }
    __syncthreads();

    int l  = tid & 63;              // phase1 interior lane
    int rr = tid >> 6;
    int wp  = (tid & 63) << 1;      // phase3: column pair
    int lh0 = (tid >> 6) << 3;      // phase3: first of 8 rows

    int cAi = 0, cBi = 0;
    if (l < 62) {
        int j0 = 4 + (l << 1);
        cAi = (j0 - 2 + sw1) * 4;
        cBi = (j0 - 2 + sw2) * 4;
    }

    float2 win[8];
    half2v hist[5][8];
#pragma unroll
    for (int k = 0; k < 8; ++k) {
        win[k].x = 0.0f; win[k].y = 0.0f;
#pragma unroll
        for (int s = 0; s < 5; ++s) hist[s][k] = half2v{(_Float16)0.0f, (_Float16)0.0f};
    }

    _Float16* dstBase = outS + (size_t)ch * CHS + (h0 + lh0) * DIM + wp;

    for (int oo = 0; oo < 4; ++oo) {
#pragma unroll
        for (int s = 0; s < 5; ++s) {
            int it = oo * 5 + s;
            int dp = clamp7(d0 - 2 + it);
            const char* pA = (const char*)(img + clamp7(dp + sd1) * PLANE);
            const char* pB = (const char*)(img + clamp7(dp + sd2) * PLANE);

            // phase 1 interior: unclamped float2 loads, j0 in [4,126]
            if (l < 62) {
                int j0 = 4 + (l << 1);
#pragma unroll
                for (int k = 0; k < 9; ++k) {
                    int r = rr + (k << 2);
                    float2 a = *(const float2*)(pA + rowA[r] + cAi);
                    float2 c = *(const float2*)(pB + rowB[r] + cBi);
                    float e0 = a.x - c.x, e1 = a.y - c.y;
                    half2v hv = { (_Float16)(e0 * e0), (_Float16)(e1 * e1) };
                    *(half2v*)&D2p[r * D2S + j0] = hv;
                }
            }
            // phase 1 edges: j0 in {0,2,128,130}, scalar double-clamp
            if (tid < 144) {
                int r  = tid >> 2;
                int pe = tid & 3;
                int j0 = (pe < 2) ? (pe << 1) : (124 + (pe << 1));
                int ra = rowA[r], rb = rowB[r];
                float dd[2];
#pragma unroll
                for (int e = 0; e < 2; ++e) {
                    int wq = clamp7(j0 + e - 2);
                    float a = *(const float*)(pA + ra + clamp7(wq + sw1) * 4);
                    float c = *(const float*)(pB + rb + clamp7(wq + sw2) * 4);
                    float df = a - c;
                    dd[e] = df * df;
                }
                half2v hv = { (_Float16)dd[0], (_Float16)dd[1] };
                *(half2v*)&D2p[r * D2S + j0] = hv;
            }
            __syncthreads();

            // phase 2: W-box, 4 outputs/unit
            for (int i = tid; i < 36 * 32; i += 256) {
                int r = i >> 5;
                int g = (i & 31) << 2;
                const half4v* src = (const half4v*)&D2p[r * D2S + g];
                half4v lo = src[0], hi = src[1];
                float l0 = lo[0], l1 = lo[1], l2 = lo[2], l3 = lo[3];
                float u0 = hi[0], u1 = hi[1], u2 = hi[2], u3 = hi[3];
                float o0 = l0 + l1 + l2 + l3 + u0;
                float o1 = o0 - l0 + u1;
                float o2 = o1 - l1 + u2;
                float o3 = o2 - l2 + u3;
                *(float4*)&T1[r * T1S + g] = make_float4(o0, o1, o2, o3);
            }
            __syncthreads();

            // phase 3: H-box (sliding 5-row col sums) -> D-window update
            {
                const float* base = &T1[lh0 * T1S + wp];
                float rx[12], ry[12];
#pragma unroll
                for (int k = 0; k < 12; ++k) {
                    float2 v = *(const float2*)(base + k * T1S);
                    rx[k] = v.x; ry[k] = v.y;
                }
                float sx = rx[0] + rx[1] + rx[2] + rx[3] + rx[4];
                float sy = ry[0] + ry[1] + ry[2] + ry[3] + ry[4];
                bool dowrite = (it >= 4);
                _Float16* dstD = dstBase + (size_t)(d0 + it - 4) * PLANE;
#pragma unroll
                for (int k = 0; k < 8; ++k) {
                    half2v hv = { (_Float16)sx, (_Float16)sy };  // round first
                    half2v old = hist[s][k];
                    win[k].x += (float)hv[0] - (float)old[0];
                    win[k].y += (float)hv[1] - (float)old[1];
                    hist[s][k] = hv;
                    if (dowrite) {
                        half2v ov = { (_Float16)win[k].x, (_Float16)win[k].y };
                        *(half2v*)(dstD + k * DIM) = ov;
                    }
                    if (k < 7) {
                        sx += rx[k + 5] - rx[k];
                        sy += ry[k + 5] - ry[k];
                    }
                }
            }
        }
    }
}

// kmse v6: 4 vox/thread, 24 independent 8-B loads up front, all-register,
// no atomics. De-aliased channel stride CHS.
__global__ __launch_bounds__(256, 3) void kmse(const _Float16* __restrict__ S0,
                                               const _Float16* __restrict__ S1,
                                               float* __restrict__ partial) {
    int t = blockIdx.x * 256 + threadIdx.x;       // 2048 blocks

    half4v v0[NCH], v1[NCH];
#pragma unroll
    for (int ch = 0; ch < NCH; ++ch)
        v0[ch] = ((const half4v*)(S0 + (size_t)ch * CHS))[t];
#pragma unroll
    for (int ch = 0; ch < NCH; ++ch)
        v1[ch] = ((const half4v*)(S1 + (size_t)ch * CHS))[t];

    float mn0[4], sm0[4], mn1[4], sm1[4];
#pragma unroll
    for (int j = 0; j < 4; ++j) {
        mn0[j] = 3.4e38f; sm0[j] = 0.0f;
        mn1[j] = 3.4e38f; sm1[j] = 0.0f;
    }
#pragma unroll
    for (int ch = 0; ch < NCH; ++ch)
#pragma unroll
        for (int j = 0; j < 4; ++j) {
            float s0 = (float)v0[ch][j];
            float s1 = (float)v1[ch][j];
            mn0[j] = fminf(mn0[j], s0); sm0[j] += s0;
            mn1[j] = fminf(mn1[j], s1); sm1[j] += s1;
        }

    float inv0[4], inv1[4];
#pragma unroll
    for (int j = 0; j < 4; ++j) {
        inv0[j] = __fdividef(1.0f, sm0[j] * (1.0f / 12.0f) - mn0[j]);
        inv1[j] = __fdividef(1.0f, sm1[j] * (1.0f / 12.0f) - mn1[j]);
    }

    float acc = 0.0f;
#pragma unroll
    for (int ch = 0; ch < NCH; ++ch)
#pragma unroll
        for (int j = 0; j < 4; ++j) {
            float e0 = __expf(-((float)v0[ch][j] - mn0[j]) * inv0[j]);
            float e1 = __expf(-((float)v1[ch][j] - mn1[j]) * inv1[j]);
            float df = e0 - e1;
            acc += df * df;
        }

#pragma unroll
    for (int off = 32; off > 0; off >>= 1)
        acc += __shfl_down(acc, off, 64);
    __shared__ float smem[4];
    int lane = threadIdx.x & 63, wv = threadIdx.x >> 6;
    if (lane == 0) smem[wv] = acc;
    __syncthreads();
    if (threadIdx.x == 0)
        partial[blockIdx.x] = smem[0] + smem[1] + smem[2] + smem[3];
}

// kred: sum 2048 partials, write the final scalar.
__global__ __launch_bounds__(256) void kred(const float* __restrict__ partial,
                                            float* __restrict__ out) {
    int tid = threadIdx.x;
    float acc = 0.0f;
#pragma unroll
    for (int k = 0; k < 8; ++k)
        acc += partial[tid + (k << 8)];
#pragma unroll
    for (int off = 32; off > 0; off >>= 1)
        acc += __shfl_down(acc, off, 64);
    __shared__ float smem[4];
    int lane = tid & 63, wv = tid >> 6;
    if (lane == 0) smem[wv] = acc;
    __syncthreads();
    if (tid == 0)
        out[0] = (smem[0] + smem[1] + smem[2] + smem[3])
               * (1.0f / (12.0f * (float)VOX));
}

__global__ void kdiag(float* out, float ws_mb) { out[0] = ws_mb; }

extern "C" void kernel_launch(void* const* d_in, const int* in_sizes, int n_in,
                              void* d_out, int out_size, void* d_ws, size_t ws_size,
                              hipStream_t stream) {
    const float* y_true = (const float*)d_in[0];
    const float* y_pred = (const float*)d_in[1];
    float* out = (float*)d_out;

    const size_t NEED = 2ull * IMGS * sizeof(_Float16) + 8192 + 64;  // ~96.2 MB
    if (ws_size < NEED) {
        kdiag<<<1, 1, 0, stream>>>(out, (float)(ws_size >> 20));
        return;
    }

    _Float16* S0      = (_Float16*)d_ws;            // ssd img0 (padded layout)
    _Float16* S1      = S0 + (size_t)IMGS;          // ssd img1
    float*    partial = (float*)(S1 + (size_t)IMGS);// 2048 floats

    f123<<<dim3(12 * 4 * 8, 2), 256, 0, stream>>>(y_true, y_pred, S0);
    kmse<<<VOX / 4 / 256, 256, 0, stream>>>(S0, S1, partial);
    kred<<<1, 256, 0, stream>>>(partial, out);
}